// Round 2
// baseline (677.758 us; speedup 1.0000x reference)
//
#include <hip/hip_runtime.h>

#define B_ 8
#define L_ 2048
#define D_ 512
#define BJ 64
#define NJB (L_ / BJ)  // 32

typedef __attribute__((ext_vector_type(4))) float  floatx4;
typedef __attribute__((ext_vector_type(8))) _Float16 halfx8;
typedef __attribute__((ext_vector_type(4))) int    intx4;

#define KSCALE 0.51012599f  // log2(e)/sqrt(8): exp2-domain softmax

static __device__ __forceinline__ unsigned short f2h_bits(float x) {
  _Float16 h = (_Float16)x;
  return __builtin_bit_cast(unsigned short, h);
}
static __device__ __forceinline__ float h2f(unsigned short b) {
  return (float)__builtin_bit_cast(_Float16, b);
}

typedef __attribute__((address_space(1))) const unsigned short gus;
typedef __attribute__((address_space(3))) unsigned short lus;
static __device__ __forceinline__ void gld_lds16(const unsigned short* g,
                                                 unsigned short* l) {
  __builtin_amdgcn_global_load_lds((gus*)g, (lus*)l, 16, 0, 0);
}

// ---------------------------------------------------------------------------
// prep: Kh[b][l][d] = in*kw (f16); Vt[b][d][l] = in*vw (f16, transposed);
//       Qh[b][l][d] = in*qw*KSCALE (f16, if ws fits).
// grid (L/64, D/64), 256 threads; batch loop inside -> weights read ONCE.
// ---------------------------------------------------------------------------
__global__ __launch_bounds__(256) void prep_kvq(const float* __restrict__ in,
                                                const float* __restrict__ qw,
                                                const float* __restrict__ kw,
                                                const float* __restrict__ vw,
                                                unsigned short* __restrict__ Kh,
                                                unsigned short* __restrict__ Vt,
                                                unsigned short* __restrict__ Qh,
                                                int has_qh) {
  const int lt = blockIdx.x * 64;
  const int dt = blockIdx.y * 64;
  const int t  = threadIdx.x;
  __shared__ unsigned short vtile[64][66];

  float4 qv[4], kv[4], vv[4];
  #pragma unroll
  for (int i = 0; i < 4; ++i) {
    int c  = i * 256 + t;
    int r  = c >> 4;
    int c4 = (c & 15) * 4;
    size_t wi_ = (size_t)(lt + r) * D_ + (dt + c4);
    qv[i] = *(const float4*)(qw + wi_);
    kv[i] = *(const float4*)(kw + wi_);
    vv[i] = *(const float4*)(vw + wi_);
  }
  for (int b = 0; b < B_; ++b) {
    #pragma unroll
    for (int i = 0; i < 4; ++i) {
      int c  = i * 256 + t;
      int r  = c >> 4;
      int c4 = (c & 15) * 4;
      size_t gi = ((size_t)b * L_ + (lt + r)) * D_ + (dt + c4);
      float4 iv = *(const float4*)(in + gi);
      uint2 pk;
      pk.x = (unsigned int)f2h_bits(iv.x * kv[i].x) |
             ((unsigned int)f2h_bits(iv.y * kv[i].y) << 16);
      pk.y = (unsigned int)f2h_bits(iv.z * kv[i].z) |
             ((unsigned int)f2h_bits(iv.w * kv[i].w) << 16);
      *(uint2*)(Kh + gi) = pk;
      if (has_qh) {
        uint2 pq;
        pq.x = (unsigned int)f2h_bits(iv.x * qv[i].x * KSCALE) |
               ((unsigned int)f2h_bits(iv.y * qv[i].y * KSCALE) << 16);
        pq.y = (unsigned int)f2h_bits(iv.z * qv[i].z * KSCALE) |
               ((unsigned int)f2h_bits(iv.w * qv[i].w * KSCALE) << 16);
        *(uint2*)(Qh + gi) = pq;
      }
      vtile[r][c4 + 0] = f2h_bits(iv.x * vv[i].x);
      vtile[r][c4 + 1] = f2h_bits(iv.y * vv[i].y);
      vtile[r][c4 + 2] = f2h_bits(iv.z * vv[i].z);
      vtile[r][c4 + 3] = f2h_bits(iv.w * vv[i].w);
    }
    __syncthreads();
    #pragma unroll
    for (int i = 0; i < 2; ++i) {
      int c  = i * 256 + t;
      int dd = c >> 3;
      int l8 = (c & 7) * 8;
      intx4 o;
      #pragma unroll
      for (int j = 0; j < 4; ++j)
        o[j] = (int)((unsigned int)vtile[l8 + 2 * j][dd] |
                     ((unsigned int)vtile[l8 + 2 * j + 1][dd] << 16));
      *(intx4*)(Vt + ((size_t)b * D_ + (dt + dd)) * L_ + (lt + l8)) = o;
    }
    __syncthreads();
  }
}

// ---------------------------------------------------------------------------
// flash: 8 waves = (wi 0..1: 32-row i-half) x (wj 0..3: 16-col j-strip for
// QK^T == 128-wide d-strip for PV). Q in regs (128 VGPR). K: swizzled LDS via
// global_load_lds prefetch. V: direct from L2 (XCD-pinned by batch).
// __launch_bounds__(512, 2): 2 waves/EU = 1 block/CU -> 256-VGPR cap, NO
// spill (round-1 failure: bare (512) capped at 128 VGPR -> ~23 MB scratch).
// grid: 256 blocks (b = bid&7 -> batch pinned per XCD), 512 threads.
// ---------------------------------------------------------------------------
__global__ __launch_bounds__(512, 2) void flash8(const float* __restrict__ in,
                                                 const float* __restrict__ qw,
                                                 const unsigned short* __restrict__ Kh,
                                                 const unsigned short* __restrict__ Vt,
                                                 const unsigned short* __restrict__ Qh,
                                                 float* __restrict__ out,
                                                 int has_qh) {
  const int bid  = blockIdx.x;
  const int b    = bid & 7;            // batch == XCD (round-robin dispatch)
  const int i0   = (bid >> 3) * 64;
  const int tid  = threadIdx.x;
  const int w    = tid >> 6;
  const int lane = tid & 63;
  const int ln16 = lane & 15;
  const int quad = lane >> 4;
  const int wi   = w >> 2;             // i-half (32 rows)
  const int wj   = w & 3;              // j-strip (16 cols) / d-strip (128)

  __shared__ unsigned short Ksh[BJ][D_];   // 64 KB, linear rows, XOR-swizzled
  __shared__ unsigned short Psh[64][72];   // 9.2 KB (+8 pad)
  __shared__ unsigned short Mpart[64][4];  // f16 max partials, 512 B
  __shared__ float          Lpart[64][4];  // f32 sum partials, 1 KB

  // ---- Q fragments: rows i0 + wi*32 + it*16 + ln16, A-layout ----
  halfx8 qf[2][16];
  if (has_qh) {
    #pragma unroll
    for (int it = 0; it < 2; ++it) {
      const unsigned short* qp =
          Qh + ((size_t)b * L_ + (i0 + wi * 32 + it * 16 + ln16)) * D_;
      #pragma unroll
      for (int ks = 0; ks < 16; ++ks)
        qf[it][ks] = *(const halfx8*)(qp + ks * 32 + quad * 8);
    }
  } else {
    #pragma unroll
    for (int it = 0; it < 2; ++it) {
      const int qi = i0 + wi * 32 + it * 16 + ln16;
      const float* ip = in + ((size_t)b * L_ + qi) * D_;
      const float* wp = qw + (size_t)qi * D_;
      #pragma unroll 4
      for (int ks = 0; ks < 16; ++ks) {
        int d0 = ks * 32 + quad * 8;
        float4 a0 = *(const float4*)(ip + d0);
        float4 a1 = *(const float4*)(ip + d0 + 4);
        float4 w0 = *(const float4*)(wp + d0);
        float4 w1 = *(const float4*)(wp + d0 + 4);
        halfx8 q;
        q[0] = (_Float16)(a0.x * w0.x * KSCALE);
        q[1] = (_Float16)(a0.y * w0.y * KSCALE);
        q[2] = (_Float16)(a0.z * w0.z * KSCALE);
        q[3] = (_Float16)(a0.w * w0.w * KSCALE);
        q[4] = (_Float16)(a1.x * w1.x * KSCALE);
        q[5] = (_Float16)(a1.y * w1.y * KSCALE);
        q[6] = (_Float16)(a1.z * w1.z * KSCALE);
        q[7] = (_Float16)(a1.w * w1.w * KSCALE);
        qf[it][ks] = q;
      }
    }
  }

  float m_r[2][4], l_w[2][4];
  #pragma unroll
  for (int it = 0; it < 2; ++it)
    #pragma unroll
    for (int r = 0; r < 4; ++r) { m_r[it][r] = -1e30f; l_w[it][r] = 0.f; }
  floatx4 O[2][8];
  #pragma unroll
  for (int it = 0; it < 2; ++it)
    #pragma unroll
    for (int ct = 0; ct < 8; ++ct) O[it][ct] = (floatx4){0.f, 0.f, 0.f, 0.f};

  // ---- prologue: DMA K tile 0 (pre-swizzled source -> linear LDS) ----
  {
    const unsigned short* kb = Kh + ((size_t)b * L_ + w * 8) * D_;
    #pragma unroll
    for (int k = 0; k < 8; ++k) {
      int r = w * 8 + k;
      gld_lds16(kb + (size_t)k * D_ + ((lane ^ (r & 7)) << 3), &Ksh[r][0]);
    }
  }
  __syncthreads();

  for (int jb = 0; jb < NJB; ++jb) {
    const int j0 = jb * BJ;

    // ---- S = Q K^T for this wave's 16 j-columns (swizzled Ksh reads) ----
    floatx4 s[2];
    s[0] = (floatx4){0.f, 0.f, 0.f, 0.f};
    s[1] = (floatx4){0.f, 0.f, 0.f, 0.f};
    const unsigned short* krp = &Ksh[wj * 16 + ln16][0];
    #pragma unroll
    for (int ks = 0; ks < 16; ++ks) {
      int cc = ((ks * 4 + quad) ^ (ln16 & 7)) << 3;
      halfx8 bk = *(const halfx8*)(krp + cc);
      s[0] = __builtin_amdgcn_mfma_f32_16x16x32_f16(qf[0][ks], bk, s[0], 0, 0, 0);
      s[1] = __builtin_amdgcn_mfma_f32_16x16x32_f16(qf[1][ks], bk, s[1], 0, 0, 0);
    }

    // ---- local (16-j) row max -> f16 partials ----
    #pragma unroll
    for (int it = 0; it < 2; ++it)
      #pragma unroll
      for (int r = 0; r < 4; ++r) {
        float m = s[it][r];
        #pragma unroll
        for (int off = 1; off < 16; off <<= 1) m = fmaxf(m, __shfl_xor(m, off));
        if (ln16 == 0)
          Mpart[wi * 32 + it * 16 + quad * 4 + r][wj] = f2h_bits(m);
      }
    __syncthreads();  // bar1: Mpart ready; Ksh consumed; prev Psh reads done

    // ---- combine max, P = exp2(S-m), per-wave l partial, rescale O ----
    #pragma unroll
    for (int it = 0; it < 2; ++it)
      #pragma unroll
      for (int r = 0; r < 4; ++r) {
        int row = wi * 32 + it * 16 + quad * 4 + r;
        uint2 mp = *(const uint2*)(&Mpart[row][0]);
        float mt = fmaxf(fmaxf(h2f((unsigned short)(mp.x & 0xffff)),
                               h2f((unsigned short)(mp.x >> 16))),
                         fmaxf(h2f((unsigned short)(mp.y & 0xffff)),
                               h2f((unsigned short)(mp.y >> 16))));
        float mn = fmaxf(m_r[it][r], mt);
        float al = exp2f(m_r[it][r] - mn);  // ==1.0f when no update
        m_r[it][r] = mn;
        float p = exp2f(s[it][r] - mn);
        Psh[row][wj * 16 + ln16] = f2h_bits(p);
        float ls = p;
        #pragma unroll
        for (int off = 1; off < 16; off <<= 1) ls += __shfl_xor(ls, off);
        l_w[it][r] = l_w[it][r] * al + ls;
        if (al != 1.0f) {
          #pragma unroll
          for (int ct = 0; ct < 8; ++ct) O[it][ct][r] *= al;
        }
      }
    __syncthreads();  // bar2: Psh ready (DMA not yet issued -> no drain cost)

    // ---- prefetch K tile jb+1 (overlaps PV; drained at bar3) ----
    if (jb + 1 < NJB) {
      const unsigned short* kb =
          Kh + ((size_t)b * L_ + j0 + BJ + w * 8) * D_;
      #pragma unroll
      for (int k = 0; k < 8; ++k) {
        int r = w * 8 + k;
        gld_lds16(kb + (size_t)k * D_ + ((lane ^ (r & 7)) << 3), &Ksh[r][0]);
      }
    }

    // ---- O += P V for this wave's 128-wide d-strip (V direct from L2) ----
    const unsigned short* vb0 =
        Vt + ((size_t)b * D_ + wj * 128) * L_ + j0 + quad * 8;
    #pragma unroll
    for (int kc = 0; kc < 2; ++kc) {
      halfx8 pf0 = *(const halfx8*)(&Psh[wi * 32 + ln16][kc * 32 + quad * 8]);
      halfx8 pf1 = *(const halfx8*)(&Psh[wi * 32 + 16 + ln16][kc * 32 + quad * 8]);
      const unsigned short* vb = vb0 + kc * 32;
      #pragma unroll
      for (int ct = 0; ct < 8; ++ct) {
        halfx8 vf = *(const halfx8*)(vb + (size_t)(ct * 16 + ln16) * L_);
        O[0][ct] = __builtin_amdgcn_mfma_f32_16x16x32_f16(pf0, vf, O[0][ct], 0, 0, 0);
        O[1][ct] = __builtin_amdgcn_mfma_f32_16x16x32_f16(pf1, vf, O[1][ct], 0, 0, 0);
      }
    }
    __syncthreads();  // bar3: vmcnt(0) drain -> Ksh[jb+1] landed; Psh free
  }

  // ---- epilogue: merge l partials, divide, store ----
  if (ln16 == 0) {
    #pragma unroll
    for (int it = 0; it < 2; ++it)
      #pragma unroll
      for (int r = 0; r < 4; ++r)
        Lpart[wi * 32 + it * 16 + quad * 4 + r][wj] = l_w[it][r];
  }
  __syncthreads();
  float inv[2][4];
  #pragma unroll
  for (int it = 0; it < 2; ++it)
    #pragma unroll
    for (int r = 0; r < 4; ++r) {
      int row = wi * 32 + it * 16 + quad * 4 + r;
      float4 lp = *(const float4*)(&Lpart[row][0]);
      inv[it][r] = 1.0f / (lp.x + lp.y + lp.z + lp.w);
    }
  #pragma unroll
  for (int it = 0; it < 2; ++it) {
    float* op = out + ((size_t)b * L_ + i0 + wi * 32 + it * 16 + quad * 4) * D_ +
                wj * 128 + ln16;
    #pragma unroll
    for (int r = 0; r < 4; ++r)
      #pragma unroll
      for (int ct = 0; ct < 8; ++ct)
        op[(size_t)r * D_ + ct * 16] = O[it][ct][r] * inv[it][r];
  }
}

// ---------------------------------------------------------------------------
extern "C" void kernel_launch(void* const* d_in, const int* in_sizes, int n_in,
                              void* d_out, int out_size, void* d_ws, size_t ws_size,
                              hipStream_t stream) {
  const float* in = (const float*)d_in[0];
  const float* qw = (const float*)d_in[1];
  const float* kw = (const float*)d_in[2];
  const float* vw = (const float*)d_in[3];
  float* out = (float*)d_out;

  const size_t seg = (size_t)B_ * L_ * D_;          // elements per f16 tensor
  unsigned short* Kh = (unsigned short*)d_ws;       // 16.78 MB
  unsigned short* Vt = Kh + seg;                    // 16.78 MB
  unsigned short* Qh = Vt + seg;                    // 16.78 MB (optional)
  const int has_qh = (ws_size >= 3 * seg * sizeof(unsigned short)) ? 1 : 0;

  dim3 gp(L_ / 64, D_ / 64);
  prep_kvq<<<gp, dim3(256), 0, stream>>>(in, qw, kw, vw, Kh, Vt, Qh, has_qh);
  flash8<<<dim3(256), dim3(512), 0, stream>>>(in, qw, Kh, Vt, Qh, out, has_qh);
}

// Round 3
// 434.237 us; speedup vs baseline: 1.5608x; 1.5608x over previous
//
#include <hip/hip_runtime.h>

#define B_ 8
#define L_ 2048
#define D_ 512
#define BJ 64
#define NJB (L_ / BJ)  // 32

typedef __attribute__((ext_vector_type(4))) float  floatx4;
typedef __attribute__((ext_vector_type(8))) _Float16 halfx8;
typedef __attribute__((ext_vector_type(4))) int    intx4;

#define KSCALE 0.51012599f  // log2(e)/sqrt(8): exp2-domain softmax

static __device__ __forceinline__ unsigned short f2h_bits(float x) {
  _Float16 h = (_Float16)x;
  return __builtin_bit_cast(unsigned short, h);
}
static __device__ __forceinline__ float h2f(unsigned short b) {
  return (float)__builtin_bit_cast(_Float16, b);
}

typedef __attribute__((address_space(1))) const unsigned short gus;
typedef __attribute__((address_space(3))) unsigned short lus;
static __device__ __forceinline__ void gld_lds16(const unsigned short* g,
                                                 unsigned short* l) {
  __builtin_amdgcn_global_load_lds((gus*)g, (lus*)l, 16, 0, 0);
}

// ---------------------------------------------------------------------------
// prep: Kh[b][l][d] = in*kw (f16); Vt[b][d][l] = in*vw (f16, transposed);
//       Qh[b][l][d] = in*qw*KSCALE (f16, if ws fits).
// grid (L/64, D/64), 256 threads; batch loop inside -> weights read ONCE.
// ---------------------------------------------------------------------------
__global__ __launch_bounds__(256) void prep_kvq(const float* __restrict__ in,
                                                const float* __restrict__ qw,
                                                const float* __restrict__ kw,
                                                const float* __restrict__ vw,
                                                unsigned short* __restrict__ Kh,
                                                unsigned short* __restrict__ Vt,
                                                unsigned short* __restrict__ Qh,
                                                int has_qh) {
  const int lt = blockIdx.x * 64;
  const int dt = blockIdx.y * 64;
  const int t  = threadIdx.x;
  __shared__ unsigned short vtile[64][66];

  float4 qv[4], kv[4], vv[4];
  #pragma unroll
  for (int i = 0; i < 4; ++i) {
    int c  = i * 256 + t;
    int r  = c >> 4;
    int c4 = (c & 15) * 4;
    size_t wi_ = (size_t)(lt + r) * D_ + (dt + c4);
    qv[i] = *(const float4*)(qw + wi_);
    kv[i] = *(const float4*)(kw + wi_);
    vv[i] = *(const float4*)(vw + wi_);
  }
  for (int b = 0; b < B_; ++b) {
    #pragma unroll
    for (int i = 0; i < 4; ++i) {
      int c  = i * 256 + t;
      int r  = c >> 4;
      int c4 = (c & 15) * 4;
      size_t gi = ((size_t)b * L_ + (lt + r)) * D_ + (dt + c4);
      float4 iv = *(const float4*)(in + gi);
      uint2 pk;
      pk.x = (unsigned int)f2h_bits(iv.x * kv[i].x) |
             ((unsigned int)f2h_bits(iv.y * kv[i].y) << 16);
      pk.y = (unsigned int)f2h_bits(iv.z * kv[i].z) |
             ((unsigned int)f2h_bits(iv.w * kv[i].w) << 16);
      *(uint2*)(Kh + gi) = pk;
      if (has_qh) {
        uint2 pq;
        pq.x = (unsigned int)f2h_bits(iv.x * qv[i].x * KSCALE) |
               ((unsigned int)f2h_bits(iv.y * qv[i].y * KSCALE) << 16);
        pq.y = (unsigned int)f2h_bits(iv.z * qv[i].z * KSCALE) |
               ((unsigned int)f2h_bits(iv.w * qv[i].w * KSCALE) << 16);
        *(uint2*)(Qh + gi) = pq;
      }
      vtile[r][c4 + 0] = f2h_bits(iv.x * vv[i].x);
      vtile[r][c4 + 1] = f2h_bits(iv.y * vv[i].y);
      vtile[r][c4 + 2] = f2h_bits(iv.z * vv[i].z);
      vtile[r][c4 + 3] = f2h_bits(iv.w * vv[i].w);
    }
    __syncthreads();
    #pragma unroll
    for (int i = 0; i < 2; ++i) {
      int c  = i * 256 + t;
      int dd = c >> 3;
      int l8 = (c & 7) * 8;
      intx4 o;
      #pragma unroll
      for (int j = 0; j < 4; ++j)
        o[j] = (int)((unsigned int)vtile[l8 + 2 * j][dd] |
                     ((unsigned int)vtile[l8 + 2 * j + 1][dd] << 16));
      *(intx4*)(Vt + ((size_t)b * D_ + (dt + dd)) * L_ + (lt + l8)) = o;
    }
    __syncthreads();
  }
}

// ---------------------------------------------------------------------------
// flash: 8 waves = (wi 0..1: 32-row i-half) x (wj 0..3: 16-col j-strip for
// QK^T == 128-wide d-strip for PV). Q in regs (128 VGPR). K: swizzled LDS via
// global_load_lds prefetch. V: direct from L2 (XCD-pinned by batch).
// __launch_bounds__(512, 2): 2 waves/EU = 1 block/CU -> 256-VGPR cap.
// RULE-20 HAZARD: every loop indexing qf/s/O MUST be fully unrolled
// (#pragma unroll, never "unroll N") or the array goes to scratch —
// round-2 regression: "unroll 4" on the Q load put qf[2][16] in scratch,
// FETCH 36 MB -> 1.07 GB, dur 366 -> 587 us.
// grid: 256 blocks (b = bid&7 -> batch pinned per XCD), 512 threads.
// ---------------------------------------------------------------------------
__global__ __launch_bounds__(512, 2) void flash8(const float* __restrict__ in,
                                                 const float* __restrict__ qw,
                                                 const unsigned short* __restrict__ Kh,
                                                 const unsigned short* __restrict__ Vt,
                                                 const unsigned short* __restrict__ Qh,
                                                 float* __restrict__ out,
                                                 int has_qh) {
  const int bid  = blockIdx.x;
  const int b    = bid & 7;            // batch == XCD (round-robin dispatch)
  const int i0   = (bid >> 3) * 64;
  const int tid  = threadIdx.x;
  const int w    = tid >> 6;
  const int lane = tid & 63;
  const int ln16 = lane & 15;
  const int quad = lane >> 4;
  const int wi   = w >> 2;             // i-half (32 rows)
  const int wj   = w & 3;              // j-strip (16 cols) / d-strip (128)

  __shared__ unsigned short Ksh[BJ][D_];   // 64 KB, linear rows, XOR-swizzled
  __shared__ unsigned short Psh[64][72];   // 9.2 KB (+8 pad)
  __shared__ unsigned short Mpart[64][4];  // f16 max partials, 512 B
  __shared__ float          Lpart[64][4];  // f32 sum partials, 1 KB

  // ---- Q fragments: rows i0 + wi*32 + it*16 + ln16, A-layout ----
  halfx8 qf[2][16];
  if (has_qh) {
    #pragma unroll
    for (int it = 0; it < 2; ++it) {
      const unsigned short* qp =
          Qh + ((size_t)b * L_ + (i0 + wi * 32 + it * 16 + ln16)) * D_;
      #pragma unroll
      for (int ks = 0; ks < 16; ++ks)
        qf[it][ks] = *(const halfx8*)(qp + ks * 32 + quad * 8);
    }
  } else {
    #pragma unroll
    for (int it = 0; it < 2; ++it) {
      const int qi = i0 + wi * 32 + it * 16 + ln16;
      const float* ip = in + ((size_t)b * L_ + qi) * D_;
      const float* wp = qw + (size_t)qi * D_;
      #pragma unroll
      for (int ks = 0; ks < 16; ++ks) {
        int d0 = ks * 32 + quad * 8;
        float4 a0 = *(const float4*)(ip + d0);
        float4 a1 = *(const float4*)(ip + d0 + 4);
        float4 w0 = *(const float4*)(wp + d0);
        float4 w1 = *(const float4*)(wp + d0 + 4);
        halfx8 q;
        q[0] = (_Float16)(a0.x * w0.x * KSCALE);
        q[1] = (_Float16)(a0.y * w0.y * KSCALE);
        q[2] = (_Float16)(a0.z * w0.z * KSCALE);
        q[3] = (_Float16)(a0.w * w0.w * KSCALE);
        q[4] = (_Float16)(a1.x * w1.x * KSCALE);
        q[5] = (_Float16)(a1.y * w1.y * KSCALE);
        q[6] = (_Float16)(a1.z * w1.z * KSCALE);
        q[7] = (_Float16)(a1.w * w1.w * KSCALE);
        qf[it][ks] = q;
      }
    }
  }

  float m_r[2][4], l_w[2][4];
  #pragma unroll
  for (int it = 0; it < 2; ++it)
    #pragma unroll
    for (int r = 0; r < 4; ++r) { m_r[it][r] = -1e30f; l_w[it][r] = 0.f; }
  floatx4 O[2][8];
  #pragma unroll
  for (int it = 0; it < 2; ++it)
    #pragma unroll
    for (int ct = 0; ct < 8; ++ct) O[it][ct] = (floatx4){0.f, 0.f, 0.f, 0.f};

  // ---- prologue: DMA K tile 0 (pre-swizzled source -> linear LDS) ----
  {
    const unsigned short* kb = Kh + ((size_t)b * L_ + w * 8) * D_;
    #pragma unroll
    for (int k = 0; k < 8; ++k) {
      int r = w * 8 + k;
      gld_lds16(kb + (size_t)k * D_ + ((lane ^ (r & 7)) << 3), &Ksh[r][0]);
    }
  }
  __syncthreads();

  for (int jb = 0; jb < NJB; ++jb) {
    const int j0 = jb * BJ;

    // ---- S = Q K^T for this wave's 16 j-columns (swizzled Ksh reads) ----
    floatx4 s[2];
    s[0] = (floatx4){0.f, 0.f, 0.f, 0.f};
    s[1] = (floatx4){0.f, 0.f, 0.f, 0.f};
    const unsigned short* krp = &Ksh[wj * 16 + ln16][0];
    #pragma unroll
    for (int ks = 0; ks < 16; ++ks) {
      int cc = ((ks * 4 + quad) ^ (ln16 & 7)) << 3;
      halfx8 bk = *(const halfx8*)(krp + cc);
      s[0] = __builtin_amdgcn_mfma_f32_16x16x32_f16(qf[0][ks], bk, s[0], 0, 0, 0);
      s[1] = __builtin_amdgcn_mfma_f32_16x16x32_f16(qf[1][ks], bk, s[1], 0, 0, 0);
    }

    // ---- local (16-j) row max -> f16 partials ----
    #pragma unroll
    for (int it = 0; it < 2; ++it)
      #pragma unroll
      for (int r = 0; r < 4; ++r) {
        float m = s[it][r];
        #pragma unroll
        for (int off = 1; off < 16; off <<= 1) m = fmaxf(m, __shfl_xor(m, off));
        if (ln16 == 0)
          Mpart[wi * 32 + it * 16 + quad * 4 + r][wj] = f2h_bits(m);
      }
    __syncthreads();  // bar1: Mpart ready; Ksh consumed; prev Psh reads done

    // ---- combine max, P = exp2(S-m), per-wave l partial, rescale O ----
    #pragma unroll
    for (int it = 0; it < 2; ++it)
      #pragma unroll
      for (int r = 0; r < 4; ++r) {
        int row = wi * 32 + it * 16 + quad * 4 + r;
        uint2 mp = *(const uint2*)(&Mpart[row][0]);
        float mt = fmaxf(fmaxf(h2f((unsigned short)(mp.x & 0xffff)),
                               h2f((unsigned short)(mp.x >> 16))),
                         fmaxf(h2f((unsigned short)(mp.y & 0xffff)),
                               h2f((unsigned short)(mp.y >> 16))));
        float mn = fmaxf(m_r[it][r], mt);
        float al = exp2f(m_r[it][r] - mn);  // ==1.0f when no update
        m_r[it][r] = mn;
        float p = exp2f(s[it][r] - mn);
        Psh[row][wj * 16 + ln16] = f2h_bits(p);
        float ls = p;
        #pragma unroll
        for (int off = 1; off < 16; off <<= 1) ls += __shfl_xor(ls, off);
        l_w[it][r] = l_w[it][r] * al + ls;
        if (al != 1.0f) {
          #pragma unroll
          for (int ct = 0; ct < 8; ++ct) O[it][ct][r] *= al;
        }
      }
    __syncthreads();  // bar2: Psh ready (DMA not yet issued -> no drain cost)

    // ---- prefetch K tile jb+1 (overlaps PV; drained at bar3) ----
    if (jb + 1 < NJB) {
      const unsigned short* kb =
          Kh + ((size_t)b * L_ + j0 + BJ + w * 8) * D_;
      #pragma unroll
      for (int k = 0; k < 8; ++k) {
        int r = w * 8 + k;
        gld_lds16(kb + (size_t)k * D_ + ((lane ^ (r & 7)) << 3), &Ksh[r][0]);
      }
    }

    // ---- O += P V for this wave's 128-wide d-strip (V direct from L2) ----
    const unsigned short* vb0 =
        Vt + ((size_t)b * D_ + wj * 128) * L_ + j0 + quad * 8;
    #pragma unroll
    for (int kc = 0; kc < 2; ++kc) {
      halfx8 pf0 = *(const halfx8*)(&Psh[wi * 32 + ln16][kc * 32 + quad * 8]);
      halfx8 pf1 = *(const halfx8*)(&Psh[wi * 32 + 16 + ln16][kc * 32 + quad * 8]);
      const unsigned short* vb = vb0 + kc * 32;
      #pragma unroll
      for (int ct = 0; ct < 8; ++ct) {
        halfx8 vf = *(const halfx8*)(vb + (size_t)(ct * 16 + ln16) * L_);
        O[0][ct] = __builtin_amdgcn_mfma_f32_16x16x32_f16(pf0, vf, O[0][ct], 0, 0, 0);
        O[1][ct] = __builtin_amdgcn_mfma_f32_16x16x32_f16(pf1, vf, O[1][ct], 0, 0, 0);
      }
    }
    __syncthreads();  // bar3: vmcnt(0) drain -> Ksh[jb+1] landed; Psh free
  }

  // ---- epilogue: merge l partials, divide, store ----
  if (ln16 == 0) {
    #pragma unroll
    for (int it = 0; it < 2; ++it)
      #pragma unroll
      for (int r = 0; r < 4; ++r)
        Lpart[wi * 32 + it * 16 + quad * 4 + r][wj] = l_w[it][r];
  }
  __syncthreads();
  float inv[2][4];
  #pragma unroll
  for (int it = 0; it < 2; ++it)
    #pragma unroll
    for (int r = 0; r < 4; ++r) {
      int row = wi * 32 + it * 16 + quad * 4 + r;
      float4 lp = *(const float4*)(&Lpart[row][0]);
      inv[it][r] = 1.0f / (lp.x + lp.y + lp.z + lp.w);
    }
  #pragma unroll
  for (int it = 0; it < 2; ++it) {
    float* op = out + ((size_t)b * L_ + i0 + wi * 32 + it * 16 + quad * 4) * D_ +
                wj * 128 + ln16;
    #pragma unroll
    for (int r = 0; r < 4; ++r)
      #pragma unroll
      for (int ct = 0; ct < 8; ++ct)
        op[(size_t)r * D_ + ct * 16] = O[it][ct][r] * inv[it][r];
  }
}

// ---------------------------------------------------------------------------
extern "C" void kernel_launch(void* const* d_in, const int* in_sizes, int n_in,
                              void* d_out, int out_size, void* d_ws, size_t ws_size,
                              hipStream_t stream) {
  const float* in = (const float*)d_in[0];
  const float* qw = (const float*)d_in[1];
  const float* kw = (const float*)d_in[2];
  const float* vw = (const float*)d_in[3];
  float* out = (float*)d_out;

  const size_t seg = (size_t)B_ * L_ * D_;          // elements per f16 tensor
  unsigned short* Kh = (unsigned short*)d_ws;       // 16.78 MB
  unsigned short* Vt = Kh + seg;                    // 16.78 MB
  unsigned short* Qh = Vt + seg;                    // 16.78 MB (optional)
  const int has_qh = (ws_size >= 3 * seg * sizeof(unsigned short)) ? 1 : 0;

  dim3 gp(L_ / 64, D_ / 64);
  prep_kvq<<<gp, dim3(256), 0, stream>>>(in, qw, kw, vw, Kh, Vt, Qh, has_qh);
  flash8<<<dim3(256), dim3(512), 0, stream>>>(in, qw, Kh, Vt, Qh, out, has_qh);
}

// Round 4
// 322.125 us; speedup vs baseline: 2.1040x; 1.3480x over previous
//
#include <hip/hip_runtime.h>

#define B_ 8
#define L_ 2048
#define D_ 512
#define BJ 64
#define NJB (L_ / BJ)  // 32

typedef __attribute__((ext_vector_type(4))) float  floatx4;
typedef __attribute__((ext_vector_type(8))) _Float16 halfx8;
typedef __attribute__((ext_vector_type(4))) int    intx4;

#define KSCALE 0.51012599f  // log2(e)/sqrt(8): exp2-domain softmax

static __device__ __forceinline__ unsigned short f2h_bits(float x) {
  _Float16 h = (_Float16)x;
  return __builtin_bit_cast(unsigned short, h);
}

typedef __attribute__((address_space(1))) const unsigned short gus;
typedef __attribute__((address_space(3))) unsigned short lus;
static __device__ __forceinline__ void gld_lds16(const unsigned short* g,
                                                 unsigned short* l) {
  __builtin_amdgcn_global_load_lds((gus*)g, (lus*)l, 16, 0, 0);
}

// ---------------------------------------------------------------------------
// prep: Kh[b][l][d] = in*kw (f16);
//       Vfrag[b][jb][dt*2+kc][lane][e] = in*vw (f16, MFMA-B fragment order:
//         lane=(quad,ln16), elem e -> V[j = jb*64 + kc*32 + quad*8 + e]
//                                      [d = dt*16 + ln16])
//       Qh[b][l][d] = in*qw*KSCALE (f16, if ws fits).
// grid (L/64, D/64), 256 threads; batch loop inside -> weights read ONCE.
// ---------------------------------------------------------------------------
__global__ __launch_bounds__(256) void prep_kvq(const float* __restrict__ in,
                                                const float* __restrict__ qw,
                                                const float* __restrict__ kw,
                                                const float* __restrict__ vw,
                                                unsigned short* __restrict__ Kh,
                                                unsigned short* __restrict__ Vfrag,
                                                unsigned short* __restrict__ Qh,
                                                int has_qh) {
  const int lt = blockIdx.x * 64;   // j-tile (== jb*64)
  const int dt = blockIdx.y * 64;   // d-tile
  const int t  = threadIdx.x;
  __shared__ unsigned short vtile[64][66];  // [j][d], +2 pad

  float4 qv[4], kv[4], vv[4];
  #pragma unroll
  for (int i = 0; i < 4; ++i) {
    int c  = i * 256 + t;
    int r  = c >> 4;
    int c4 = (c & 15) * 4;
    size_t wi_ = (size_t)(lt + r) * D_ + (dt + c4);
    qv[i] = *(const float4*)(qw + wi_);
    kv[i] = *(const float4*)(kw + wi_);
    vv[i] = *(const float4*)(vw + wi_);
  }
  const int wv   = t >> 6;    // wave 0..3
  const int ln   = t & 63;
  const int q4   = ln >> 4;   // quad
  const int l16  = ln & 15;
  for (int b = 0; b < B_; ++b) {
    #pragma unroll
    for (int i = 0; i < 4; ++i) {
      int c  = i * 256 + t;
      int r  = c >> 4;
      int c4 = (c & 15) * 4;
      size_t gi = ((size_t)b * L_ + (lt + r)) * D_ + (dt + c4);
      float4 iv = *(const float4*)(in + gi);
      uint2 pk;
      pk.x = (unsigned int)f2h_bits(iv.x * kv[i].x) |
             ((unsigned int)f2h_bits(iv.y * kv[i].y) << 16);
      pk.y = (unsigned int)f2h_bits(iv.z * kv[i].z) |
             ((unsigned int)f2h_bits(iv.w * kv[i].w) << 16);
      *(uint2*)(Kh + gi) = pk;
      if (has_qh) {
        uint2 pq;
        pq.x = (unsigned int)f2h_bits(iv.x * qv[i].x * KSCALE) |
               ((unsigned int)f2h_bits(iv.y * qv[i].y * KSCALE) << 16);
        pq.y = (unsigned int)f2h_bits(iv.z * qv[i].z * KSCALE) |
               ((unsigned int)f2h_bits(iv.w * qv[i].w * KSCALE) << 16);
        *(uint2*)(Qh + gi) = pq;
      }
      vtile[r][c4 + 0] = f2h_bits(iv.x * vv[i].x);
      vtile[r][c4 + 1] = f2h_bits(iv.y * vv[i].y);
      vtile[r][c4 + 2] = f2h_bits(iv.z * vv[i].z);
      vtile[r][c4 + 3] = f2h_bits(iv.w * vv[i].w);
    }
    __syncthreads();
    // ---- write V in MFMA fragment order: 8 1-KB chunks, 2 per wave ----
    #pragma unroll
    for (int i = 0; i < 2; ++i) {
      int ch  = wv * 2 + i;        // 0..7
      int dtl = ch >> 1;           // local d-tile 0..3
      int kc  = ch & 1;            // j-half 0..1
      int ov[4];
      #pragma unroll
      for (int j = 0; j < 4; ++j) {
        int e0 = 2 * j;
        ov[j] = (int)((unsigned int)vtile[kc * 32 + q4 * 8 + e0][dtl * 16 + l16] |
                      ((unsigned int)vtile[kc * 32 + q4 * 8 + e0 + 1][dtl * 16 + l16] << 16));
      }
      intx4 o; o[0] = ov[0]; o[1] = ov[1]; o[2] = ov[2]; o[3] = ov[3];
      size_t off = ((((size_t)b * NJB + (lt >> 6)) * 64) +
                    ((size_t)(dt >> 4) + dtl) * 2 + kc) * 512 + (size_t)ln * 8;
      *(intx4*)(Vfrag + off) = o;
    }
    __syncthreads();
  }
}

// ---------------------------------------------------------------------------
// flash: 8 waves, THREE roles per jb (k-split keeps Q at 32 VGPR/wave):
//  QK^T: wave (wi=w>>2, wk=w&3): rows wi*32..+32, k-slice wk*128..+128 ->
//        partial S to Ssh[wk] (f32, XOR-swizzled, conflict-free).
//  merge/softmax: wave (wi,wk) owns rows wi*32+wk*8..+8: sums 4 partials,
//        full-row max via 6-step shuffle, m/l state local, P->Psh,
//        alpha->Alsh (broadcast to PV waves).
//  PV: wave (wi_p=w>>2, wd=w&3): O[2][8] (64 AGPRs) over d-strip wd*128,
//        V fragments loaded lane-contiguous (1 KB) from Vfrag via L2
//        (batch pinned per XCD by b=bid&7).
// Registers: qf 32 + O 64 + state 16 + temps -> ~190 total, fits 256 cap of
// __launch_bounds__(512,2); rounds 1-3 spilled because qf[2][16]=128 alone.
// RULE-20: every loop indexing qf/s_p/O/m_r/l_r MUST be fully unrolled.
// LDS: 64(Ksh)+64(Ssh)+9.2(Psh)+0.5 = 138 KB -> 1 block/CU, 8 waves.
// 3 barriers/jb; K DMA issued after barC, drained at barD (overlaps PV).
// ---------------------------------------------------------------------------
__global__ __launch_bounds__(512, 2) void flash8(const float* __restrict__ in,
                                                 const float* __restrict__ qw,
                                                 const unsigned short* __restrict__ Kh,
                                                 const unsigned short* __restrict__ Vfrag,
                                                 const unsigned short* __restrict__ Qh,
                                                 float* __restrict__ out,
                                                 int has_qh) {
  const int bid  = blockIdx.x;
  const int b    = bid & 7;            // batch == XCD (round-robin dispatch)
  const int i0   = (bid >> 3) * 64;
  const int tid  = threadIdx.x;
  const int w    = tid >> 6;
  const int lane = tid & 63;
  const int ln16 = lane & 15;
  const int quad = lane >> 4;
  const int wi   = w >> 2;             // i-half (32 rows) for QK^T + PV
  const int wk   = w & 3;              // k-slice (QK^T) / merge row-group / d-strip (PV)

  __shared__ unsigned short Ksh[BJ][D_];   // 64 KB, rows XOR^(r&15)-swizzled
  __shared__ float Ssh[4][BJ][BJ];         // 64 KB partial S, XOR-swizzled
  __shared__ unsigned short Psh[64][72];   // 9.2 KB
  __shared__ float Alsh[64];               // per-jb rescale alpha
  __shared__ float Lsh[64];                // final l

  // ---- Q fragments: 32 rows x k-slice 128 -> qf[2][4] = 32 VGPRs ----
  halfx8 qf[2][4];
  if (has_qh) {
    #pragma unroll
    for (int it = 0; it < 2; ++it) {
      const unsigned short* qp =
          Qh + ((size_t)b * L_ + (i0 + wi * 32 + it * 16 + ln16)) * D_ + wk * 128;
      #pragma unroll
      for (int ks = 0; ks < 4; ++ks)
        qf[it][ks] = *(const halfx8*)(qp + ks * 32 + quad * 8);
    }
  } else {
    #pragma unroll
    for (int it = 0; it < 2; ++it) {
      const int qi = i0 + wi * 32 + it * 16 + ln16;
      const float* ip = in + ((size_t)b * L_ + qi) * D_ + wk * 128;
      const float* wp = qw + (size_t)qi * D_ + wk * 128;
      #pragma unroll
      for (int ks = 0; ks < 4; ++ks) {
        int d0 = ks * 32 + quad * 8;
        float4 a0 = *(const float4*)(ip + d0);
        float4 a1 = *(const float4*)(ip + d0 + 4);
        float4 w0 = *(const float4*)(wp + d0);
        float4 w1 = *(const float4*)(wp + d0 + 4);
        halfx8 q;
        q[0] = (_Float16)(a0.x * w0.x * KSCALE);
        q[1] = (_Float16)(a0.y * w0.y * KSCALE);
        q[2] = (_Float16)(a0.z * w0.z * KSCALE);
        q[3] = (_Float16)(a0.w * w0.w * KSCALE);
        q[4] = (_Float16)(a1.x * w1.x * KSCALE);
        q[5] = (_Float16)(a1.y * w1.y * KSCALE);
        q[6] = (_Float16)(a1.z * w1.z * KSCALE);
        q[7] = (_Float16)(a1.w * w1.w * KSCALE);
        qf[it][ks] = q;
      }
    }
  }

  // merge-role state: full m/l for rows  wi*32 + wk*8 + rr
  float m_r[8], l_r[8];
  #pragma unroll
  for (int rr = 0; rr < 8; ++rr) { m_r[rr] = -1e30f; l_r[rr] = 0.f; }
  floatx4 O[2][8];
  #pragma unroll
  for (int it = 0; it < 2; ++it)
    #pragma unroll
    for (int ct = 0; ct < 8; ++ct) O[it][ct] = (floatx4){0.f, 0.f, 0.f, 0.f};

  // ---- prologue: DMA K tile 0 (pre-swizzled source -> linear LDS) ----
  {
    const unsigned short* kb = Kh + ((size_t)b * L_ + w * 8) * D_;
    #pragma unroll
    for (int k = 0; k < 8; ++k) {
      int r = w * 8 + k;
      gld_lds16(kb + (size_t)k * D_ + ((lane ^ (r & 15)) << 3), &Ksh[r][0]);
    }
  }
  __syncthreads();

  const unsigned short* vfbase =
      Vfrag + ((size_t)b * NJB) * 64 * 512 + (size_t)lane * 8;

  for (int jb = 0; jb < NJB; ++jb) {
    // ======== phase 1: partial QK^T over k-slice wk (swizzled Ksh) ========
    floatx4 s_p[2][4];
    #pragma unroll
    for (int it = 0; it < 2; ++it)
      #pragma unroll
      for (int jt = 0; jt < 4; ++jt) s_p[it][jt] = (floatx4){0.f, 0.f, 0.f, 0.f};
    #pragma unroll
    for (int jt = 0; jt < 4; ++jt) {
      const unsigned short* krp = &Ksh[jt * 16 + ln16][0];
      #pragma unroll
      for (int ks = 0; ks < 4; ++ks) {
        int cc = ((wk * 16 + ks * 4 + quad) ^ ln16) << 3;
        halfx8 bk = *(const halfx8*)(krp + cc);
        s_p[0][jt] = __builtin_amdgcn_mfma_f32_16x16x32_f16(qf[0][ks], bk, s_p[0][jt], 0, 0, 0);
        s_p[1][jt] = __builtin_amdgcn_mfma_f32_16x16x32_f16(qf[1][ks], bk, s_p[1][jt], 0, 0, 0);
      }
    }
    // write partials: Ssh[wk][row][j ^ (quad<<3)]  (conflict-free)
    #pragma unroll
    for (int it = 0; it < 2; ++it)
      #pragma unroll
      for (int jt = 0; jt < 4; ++jt)
        #pragma unroll
        for (int r = 0; r < 4; ++r)
          Ssh[wk][wi * 32 + it * 16 + quad * 4 + r][(jt * 16 + ln16) ^ (quad << 3)] =
              s_p[it][jt][r];
    __syncthreads();  // barA: Ssh ready, Ksh consumed

    // ======== phase 2: merge k-partials + full-row online softmax ========
    // rows  lrow = wi*32 + wk*8 + rr ; this lane holds column j = lane
    #pragma unroll
    for (int rr = 0; rr < 8; ++rr) {
      int lrow = wi * 32 + wk * 8 + rr;
      int jj = lane ^ (((lrow >> 2) & 3) << 3);
      float sv = (Ssh[0][lrow][jj] + Ssh[1][lrow][jj]) +
                 (Ssh[2][lrow][jj] + Ssh[3][lrow][jj]);
      float mx = sv;
      #pragma unroll
      for (int off = 1; off < 64; off <<= 1) mx = fmaxf(mx, __shfl_xor(mx, off));
      float mn = fmaxf(m_r[rr], mx);
      float al = exp2f(m_r[rr] - mn);   // 1.0 when no update, 0 on first tile
      m_r[rr] = mn;
      float p = exp2f(sv - mn);
      Psh[lrow][lane] = f2h_bits(p);
      float ls = p;
      #pragma unroll
      for (int off = 1; off < 64; off <<= 1) ls += __shfl_xor(ls, off);
      l_r[rr] = l_r[rr] * al + ls;
      if (lane == 0) Alsh[lrow] = al;
    }
    __syncthreads();  // barC: Psh/Alsh ready

    // ---- prefetch K tile jb+1 (overlaps PV; drained at barD) ----
    if (jb + 1 < NJB) {
      const unsigned short* kb = Kh + ((size_t)b * L_ + (jb + 1) * BJ + w * 8) * D_;
      #pragma unroll
      for (int k = 0; k < 8; ++k) {
        int r = w * 8 + k;
        gld_lds16(kb + (size_t)k * D_ + ((lane ^ (r & 15)) << 3), &Ksh[r][0]);
      }
    }

    // ======== phase 3: O rescale + PV over d-strip wk*128 ========
    // (PV role: wi_p = wi, wd = wk)
    #pragma unroll
    for (int it = 0; it < 2; ++it) {
      float4 alv = *(const float4*)(&Alsh[wi * 32 + it * 16 + quad * 4]);
      #pragma unroll
      for (int ct = 0; ct < 8; ++ct) {
        O[it][ct][0] *= alv.x; O[it][ct][1] *= alv.y;
        O[it][ct][2] *= alv.z; O[it][ct][3] *= alv.w;
      }
    }
    halfx8 pf[2][2];
    #pragma unroll
    for (int it = 0; it < 2; ++it)
      #pragma unroll
      for (int kc = 0; kc < 2; ++kc)
        pf[it][kc] = *(const halfx8*)(&Psh[wi * 32 + it * 16 + ln16][kc * 32 + quad * 8]);
    const unsigned short* vjb = vfbase + ((size_t)jb * 64 + (size_t)wk * 16) * 512;
    #pragma unroll
    for (int ct = 0; ct < 8; ++ct) {
      #pragma unroll
      for (int kc = 0; kc < 2; ++kc) {
        halfx8 vf = *(const halfx8*)(vjb + (ct * 2 + kc) * 512);
        O[0][ct] = __builtin_amdgcn_mfma_f32_16x16x32_f16(pf[0][kc], vf, O[0][ct], 0, 0, 0);
        O[1][ct] = __builtin_amdgcn_mfma_f32_16x16x32_f16(pf[1][kc], vf, O[1][ct], 0, 0, 0);
      }
    }
    __syncthreads();  // barD: next K landed (vmcnt drain), Psh/Ssh free
  }

  // ---- epilogue: publish l, divide, store ----
  if (lane == 0) {
    #pragma unroll
    for (int rr = 0; rr < 8; ++rr) Lsh[wi * 32 + wk * 8 + rr] = l_r[rr];
  }
  __syncthreads();
  #pragma unroll
  for (int it = 0; it < 2; ++it) {
    float4 lv = *(const float4*)(&Lsh[wi * 32 + it * 16 + quad * 4]);
    float i0v = 1.0f / lv.x, i1v = 1.0f / lv.y, i2v = 1.0f / lv.z, i3v = 1.0f / lv.w;
    float* op = out + ((size_t)b * L_ + i0 + wi * 32 + it * 16 + quad * 4) * D_ +
                wk * 128 + ln16;
    #pragma unroll
    for (int ct = 0; ct < 8; ++ct) {
      op[(size_t)0 * D_ + ct * 16] = O[it][ct][0] * i0v;
      op[(size_t)1 * D_ + ct * 16] = O[it][ct][1] * i1v;
      op[(size_t)2 * D_ + ct * 16] = O[it][ct][2] * i2v;
      op[(size_t)3 * D_ + ct * 16] = O[it][ct][3] * i3v;
    }
  }
}

// ---------------------------------------------------------------------------
extern "C" void kernel_launch(void* const* d_in, const int* in_sizes, int n_in,
                              void* d_out, int out_size, void* d_ws, size_t ws_size,
                              hipStream_t stream) {
  const float* in = (const float*)d_in[0];
  const float* qw = (const float*)d_in[1];
  const float* kw = (const float*)d_in[2];
  const float* vw = (const float*)d_in[3];
  float* out = (float*)d_out;

  const size_t seg = (size_t)B_ * L_ * D_;          // elements per f16 tensor
  unsigned short* Kh = (unsigned short*)d_ws;       // 16.78 MB
  unsigned short* Vf = Kh + seg;                    // 16.78 MB (fragment order)
  unsigned short* Qh = Vf + seg;                    // 16.78 MB (optional)
  const int has_qh = (ws_size >= 3 * seg * sizeof(unsigned short)) ? 1 : 0;

  dim3 gp(L_ / 64, D_ / 64);
  prep_kvq<<<gp, dim3(256), 0, stream>>>(in, qw, kw, vw, Kh, Vf, Qh, has_qh);
  flash8<<<dim3(256), dim3(512), 0, stream>>>(in, qw, Kh, Vf, Qh, out, has_qh);
}

// Round 5
// 254.689 us; speedup vs baseline: 2.6611x; 1.2648x over previous
//
#include <hip/hip_runtime.h>

#define B_ 8
#define L_ 2048
#define D_ 512
#define BI 128            // i-rows per block
#define BJ 64
#define NJB (L_ / BJ)     // 32
#define NDH 2             // D-halves across blocks

typedef __attribute__((ext_vector_type(4))) float  floatx4;
typedef __attribute__((ext_vector_type(8))) _Float16 halfx8;
typedef __attribute__((ext_vector_type(4))) int    intx4;

#define KSCALE 0.51012599f  // log2(e)/sqrt(8): exp2-domain softmax

static __device__ __forceinline__ unsigned short f2h_bits(float x) {
  _Float16 h = (_Float16)x;
  return __builtin_bit_cast(unsigned short, h);
}

typedef __attribute__((address_space(1))) const unsigned short gus;
typedef __attribute__((address_space(3))) unsigned short lus;
static __device__ __forceinline__ void gld_lds16(const unsigned short* g,
                                                 unsigned short* l) {
  __builtin_amdgcn_global_load_lds((gus*)g, (lus*)l, 16, 0, 0);
}

// ---------------------------------------------------------------------------
// prep: Kh[b][l][d] = in*kw (f16);
//       Vfrag[b][jb][d16*2+kc][lane][e] = in*vw (f16, MFMA-B fragment order:
//         lane=(quad,ln16), elem e -> V[j = jb*64 + kc*32 + quad*8 + e]
//                                      [d = d16*16 + ln16])
//       Qh[b][l][d] = in*qw*KSCALE (f16, if ws fits).
// grid (L/64, D/64), 256 threads; batch loop inside -> weights read ONCE.
// (unchanged from round 4 — proven correct)
// ---------------------------------------------------------------------------
__global__ __launch_bounds__(256) void prep_kvq(const float* __restrict__ in,
                                                const float* __restrict__ qw,
                                                const float* __restrict__ kw,
                                                const float* __restrict__ vw,
                                                unsigned short* __restrict__ Kh,
                                                unsigned short* __restrict__ Vfrag,
                                                unsigned short* __restrict__ Qh,
                                                int has_qh) {
  const int lt = blockIdx.x * 64;   // j-tile (== jb*64)
  const int dt = blockIdx.y * 64;   // d-tile
  const int t  = threadIdx.x;
  __shared__ unsigned short vtile[64][66];  // [j][d], +2 pad

  float4 qv[4], kv[4], vv[4];
  #pragma unroll
  for (int i = 0; i < 4; ++i) {
    int c  = i * 256 + t;
    int r  = c >> 4;
    int c4 = (c & 15) * 4;
    size_t wi_ = (size_t)(lt + r) * D_ + (dt + c4);
    qv[i] = *(const float4*)(qw + wi_);
    kv[i] = *(const float4*)(kw + wi_);
    vv[i] = *(const float4*)(vw + wi_);
  }
  const int wv   = t >> 6;    // wave 0..3
  const int ln   = t & 63;
  const int q4   = ln >> 4;   // quad
  const int l16  = ln & 15;
  for (int b = 0; b < B_; ++b) {
    #pragma unroll
    for (int i = 0; i < 4; ++i) {
      int c  = i * 256 + t;
      int r  = c >> 4;
      int c4 = (c & 15) * 4;
      size_t gi = ((size_t)b * L_ + (lt + r)) * D_ + (dt + c4);
      float4 iv = *(const float4*)(in + gi);
      uint2 pk;
      pk.x = (unsigned int)f2h_bits(iv.x * kv[i].x) |
             ((unsigned int)f2h_bits(iv.y * kv[i].y) << 16);
      pk.y = (unsigned int)f2h_bits(iv.z * kv[i].z) |
             ((unsigned int)f2h_bits(iv.w * kv[i].w) << 16);
      *(uint2*)(Kh + gi) = pk;
      if (has_qh) {
        uint2 pq;
        pq.x = (unsigned int)f2h_bits(iv.x * qv[i].x * KSCALE) |
               ((unsigned int)f2h_bits(iv.y * qv[i].y * KSCALE) << 16);
        pq.y = (unsigned int)f2h_bits(iv.z * qv[i].z * KSCALE) |
               ((unsigned int)f2h_bits(iv.w * qv[i].w * KSCALE) << 16);
        *(uint2*)(Qh + gi) = pq;
      }
      vtile[r][c4 + 0] = f2h_bits(iv.x * vv[i].x);
      vtile[r][c4 + 1] = f2h_bits(iv.y * vv[i].y);
      vtile[r][c4 + 2] = f2h_bits(iv.z * vv[i].z);
      vtile[r][c4 + 3] = f2h_bits(iv.w * vv[i].w);
    }
    __syncthreads();
    #pragma unroll
    for (int i = 0; i < 2; ++i) {
      int ch  = wv * 2 + i;        // 0..7
      int dtl = ch >> 1;           // local d-tile 0..3
      int kc  = ch & 1;            // j-half 0..1
      int ov[4];
      #pragma unroll
      for (int j = 0; j < 4; ++j) {
        int e0 = 2 * j;
        ov[j] = (int)((unsigned int)vtile[kc * 32 + q4 * 8 + e0][dtl * 16 + l16] |
                      ((unsigned int)vtile[kc * 32 + q4 * 8 + e0 + 1][dtl * 16 + l16] << 16));
      }
      intx4 o; o[0] = ov[0]; o[1] = ov[1]; o[2] = ov[2]; o[3] = ov[3];
      size_t off = ((((size_t)b * NJB + (lt >> 6)) * 64) +
                    ((size_t)(dt >> 4) + dtl) * 2 + kc) * 512 + (size_t)ln * 8;
      *(intx4*)(Vfrag + off) = o;
    }
    __syncthreads();
  }
}

// ---------------------------------------------------------------------------
// flash v6 — traffic-minimized (fabric/L3-BW-bound analysis, rounds 0-4):
//  grid 256 = b(&7, XCD-pin) x i-tile(16, BI=128) x dh(2, 256-wide D-half).
//  8 waves, 512 thr, __launch_bounds__(512,2) -> 256-VGPR cap.
//  QK^T: wave w owns UNIQUE 16-row Q A-tile (qf[16]=64 VGPR, full K=512),
//        full 64 j per wave -> softmax is WAVE-LOCAL (no cross-wave merge).
//        S duplicated across the 2 dh-blocks (MFMA is cheap; bytes are not).
//  PV:   wave w owns UNIQUE 32-wide d-strip of this block's D-half;
//        V staged ONCE (32 KB/jb); O[8][2]=64 VGPR for all 128 rows.
//  K: double-buffered LDS via global_load_lds (XOR^(r&15) pre-swizzled src).
//  Staging 96 KB/jb/block (was 192): total 786 MB vs round-4's 1.6 GB.
//  RULE-20: every loop indexing qf/s/O/vf MUST be fully unrolled.
// ---------------------------------------------------------------------------
__global__ __launch_bounds__(512, 2) void flash8(const float* __restrict__ in,
                                                 const float* __restrict__ qw,
                                                 const unsigned short* __restrict__ Kh,
                                                 const unsigned short* __restrict__ Vfrag,
                                                 const unsigned short* __restrict__ Qh,
                                                 float* __restrict__ out,
                                                 int has_qh) {
  const int bid  = blockIdx.x;
  const int b    = bid & 7;            // batch == XCD (round-robin dispatch)
  const int t2   = bid >> 3;
  const int it_  = t2 & 15;            // i-tile
  const int dh   = t2 >> 4;            // D-half 0..1
  const int i0   = it_ * BI;
  const int tid  = threadIdx.x;
  const int w    = tid >> 6;
  const int lane = tid & 63;
  const int ln16 = lane & 15;
  const int quad = lane >> 4;

  __shared__ unsigned short Ksh[2][BJ][D_];  // 128 KB double-buffered
  __shared__ unsigned short Psh[BI][72];     // 18.4 KB
  __shared__ float Alsh[BI];                 // per-jb rescale alpha
  __shared__ float Lsh[BI];                  // final l

  // ---- Q fragments: rows i0 + w*16 + ln16, full K, A-layout ----
  halfx8 qf[16];
  if (has_qh) {
    const unsigned short* qp =
        Qh + ((size_t)b * L_ + (i0 + w * 16 + ln16)) * D_;
    #pragma unroll
    for (int ks = 0; ks < 16; ++ks)
      qf[ks] = *(const halfx8*)(qp + ks * 32 + quad * 8);
  } else {
    const int qi = i0 + w * 16 + ln16;
    const float* ip = in + ((size_t)b * L_ + qi) * D_;
    const float* wp = qw + (size_t)qi * D_;
    #pragma unroll
    for (int ks = 0; ks < 16; ++ks) {
      int d0 = ks * 32 + quad * 8;
      float4 a0 = *(const float4*)(ip + d0);
      float4 a1 = *(const float4*)(ip + d0 + 4);
      float4 w0 = *(const float4*)(wp + d0);
      float4 w1 = *(const float4*)(wp + d0 + 4);
      halfx8 q;
      q[0] = (_Float16)(a0.x * w0.x * KSCALE);
      q[1] = (_Float16)(a0.y * w0.y * KSCALE);
      q[2] = (_Float16)(a0.z * w0.z * KSCALE);
      q[3] = (_Float16)(a0.w * w0.w * KSCALE);
      q[4] = (_Float16)(a1.x * w1.x * KSCALE);
      q[5] = (_Float16)(a1.y * w1.y * KSCALE);
      q[6] = (_Float16)(a1.z * w1.z * KSCALE);
      q[7] = (_Float16)(a1.w * w1.w * KSCALE);
      qf[ks] = q;
    }
  }

  // softmax state for this wave's 16 rows (row = w*16 + quad*4 + r)
  float m_r[4], l_r[4];
  #pragma unroll
  for (int r = 0; r < 4; ++r) { m_r[r] = -1e30f; l_r[r] = 0.f; }
  // O accumulator: all 128 rows x this wave's 32-wide d-strip
  floatx4 O[8][2];
  #pragma unroll
  for (int rt = 0; rt < 8; ++rt) {
    O[rt][0] = (floatx4){0.f, 0.f, 0.f, 0.f};
    O[rt][1] = (floatx4){0.f, 0.f, 0.f, 0.f};
  }

  // ---- prologue: DMA K tile 0 into buf0 (pre-swizzled source) ----
  {
    const unsigned short* kb = Kh + ((size_t)b * L_ + w * 8) * D_;
    #pragma unroll
    for (int k = 0; k < 8; ++k) {
      int r = w * 8 + k;
      gld_lds16(kb + (size_t)k * D_ + ((lane ^ (r & 15)) << 3), &Ksh[0][r][0]);
    }
  }
  __syncthreads();

  int buf = 0;
  for (int jb = 0; jb < NJB; ++jb) {
    // ======== phase 1: full QK^T (16 rows x 64 j) + wave-local softmax ====
    floatx4 s[4];
    s[0] = (floatx4){0.f, 0.f, 0.f, 0.f};
    s[1] = (floatx4){0.f, 0.f, 0.f, 0.f};
    s[2] = (floatx4){0.f, 0.f, 0.f, 0.f};
    s[3] = (floatx4){0.f, 0.f, 0.f, 0.f};
    #pragma unroll
    for (int ks = 0; ks < 16; ++ks) {
      #pragma unroll
      for (int jt = 0; jt < 4; ++jt) {
        halfx8 bk = *(const halfx8*)(
            &Ksh[buf][jt * 16 + ln16][((ks * 4 + quad) ^ ln16) << 3]);
        s[jt] = __builtin_amdgcn_mfma_f32_16x16x32_f16(qf[ks], bk, s[jt], 0, 0, 0);
      }
    }
    #pragma unroll
    for (int r = 0; r < 4; ++r) {
      float mx = fmaxf(fmaxf(s[0][r], s[1][r]), fmaxf(s[2][r], s[3][r]));
      #pragma unroll
      for (int off = 1; off < 16; off <<= 1) mx = fmaxf(mx, __shfl_xor(mx, off));
      float mn = fmaxf(m_r[r], mx);
      float al = exp2f(m_r[r] - mn);   // 1.0 when no update, 0 on first tile
      m_r[r] = mn;
      int row = w * 16 + quad * 4 + r;
      float ls = 0.f;
      #pragma unroll
      for (int jt = 0; jt < 4; ++jt) {
        float p = exp2f(s[jt][r] - mn);
        Psh[row][jt * 16 + ln16] = f2h_bits(p);
        ls += p;
      }
      #pragma unroll
      for (int off = 1; off < 16; off <<= 1) ls += __shfl_xor(ls, off);
      l_r[r] = l_r[r] * al + ls;
      if (ln16 == 0) Alsh[row] = al;
    }
    __syncthreads();  // barA: Psh/Alsh ready; Ksh[buf] consumed

    // ======== phase 2: PV over this wave's 32-wide d-strip ========
    // V loads first (1 KB lane-contiguous each), then next-K DMA issue —
    // both drain together at barB.
    halfx8 vf[2][2];
    {
      const unsigned short* vb =
          Vfrag + (((size_t)b * NJB + jb) * 64) * 512 + (size_t)lane * 8;
      #pragma unroll
      for (int dt = 0; dt < 2; ++dt)
        #pragma unroll
        for (int kc = 0; kc < 2; ++kc)
          vf[dt][kc] = *(const halfx8*)(
              vb + (size_t)(((dh * 16 + w * 2 + dt) * 2 + kc)) * 512);
    }
    if (jb + 1 < NJB) {
      const unsigned short* kb =
          Kh + ((size_t)b * L_ + (jb + 1) * BJ + w * 8) * D_;
      #pragma unroll
      for (int k = 0; k < 8; ++k) {
        int r = w * 8 + k;
        gld_lds16(kb + (size_t)k * D_ + ((lane ^ (r & 15)) << 3),
                  &Ksh[buf ^ 1][r][0]);
      }
    }
    // rescale O by per-row alpha
    #pragma unroll
    for (int rt = 0; rt < 8; ++rt) {
      float4 alv = *(const float4*)(&Alsh[rt * 16 + quad * 4]);
      #pragma unroll
      for (int dt = 0; dt < 2; ++dt) {
        O[rt][dt][0] *= alv.x; O[rt][dt][1] *= alv.y;
        O[rt][dt][2] *= alv.z; O[rt][dt][3] *= alv.w;
      }
    }
    // O += P V
    #pragma unroll
    for (int rt = 0; rt < 8; ++rt) {
      #pragma unroll
      for (int kc = 0; kc < 2; ++kc) {
        halfx8 pf = *(const halfx8*)(&Psh[rt * 16 + ln16][kc * 32 + quad * 8]);
        O[rt][0] = __builtin_amdgcn_mfma_f32_16x16x32_f16(pf, vf[0][kc], O[rt][0], 0, 0, 0);
        O[rt][1] = __builtin_amdgcn_mfma_f32_16x16x32_f16(pf, vf[1][kc], O[rt][1], 0, 0, 0);
      }
    }
    __syncthreads();  // barB: vmcnt(0) drain -> next K landed; Psh/Alsh free
    buf ^= 1;
  }

  // ---- epilogue: publish l, divide, store this block's D-half ----
  if (ln16 == 0) {
    #pragma unroll
    for (int r = 0; r < 4; ++r) Lsh[w * 16 + quad * 4 + r] = l_r[r];
  }
  __syncthreads();
  #pragma unroll
  for (int rt = 0; rt < 8; ++rt) {
    float4 lv = *(const float4*)(&Lsh[rt * 16 + quad * 4]);
    float i0v = 1.0f / lv.x, i1v = 1.0f / lv.y;
    float i2v = 1.0f / lv.z, i3v = 1.0f / lv.w;
    float* op = out + ((size_t)b * L_ + i0 + rt * 16 + quad * 4) * D_ +
                dh * 256 + w * 32 + ln16;
    #pragma unroll
    for (int dt = 0; dt < 2; ++dt) {
      op[(size_t)0 * D_ + dt * 16] = O[rt][dt][0] * i0v;
      op[(size_t)1 * D_ + dt * 16] = O[rt][dt][1] * i1v;
      op[(size_t)2 * D_ + dt * 16] = O[rt][dt][2] * i2v;
      op[(size_t)3 * D_ + dt * 16] = O[rt][dt][3] * i3v;
    }
  }
}

// ---------------------------------------------------------------------------
extern "C" void kernel_launch(void* const* d_in, const int* in_sizes, int n_in,
                              void* d_out, int out_size, void* d_ws, size_t ws_size,
                              hipStream_t stream) {
  const float* in = (const float*)d_in[0];
  const float* qw = (const float*)d_in[1];
  const float* kw = (const float*)d_in[2];
  const float* vw = (const float*)d_in[3];
  float* out = (float*)d_out;

  const size_t seg = (size_t)B_ * L_ * D_;          // elements per f16 tensor
  unsigned short* Kh = (unsigned short*)d_ws;       // 16.78 MB
  unsigned short* Vf = Kh + seg;                    // 16.78 MB (fragment order)
  unsigned short* Qh = Vf + seg;                    // 16.78 MB (optional)
  const int has_qh = (ws_size >= 3 * seg * sizeof(unsigned short)) ? 1 : 0;

  dim3 gp(L_ / 64, D_ / 64);
  prep_kvq<<<gp, dim3(256), 0, stream>>>(in, qw, kw, vw, Kh, Vf, Qh, has_qh);
  flash8<<<dim3(256), dim3(512), 0, stream>>>(in, qw, Kh, Vf, Qh, out, has_qh);
}